// Round 18
// baseline (981.707 us; speedup 1.0000x reference)
//
#include <hip/hip_runtime.h>
#include <math.h>

#define N_NODES 50000
#define N_EDGES 800000
#define D 64

#define NB 256                    // dst buckets
#define NBLK 256                  // blocks in bucket hist/scatter
#define BUCKET_NODES 196          // ceil(50000/256); 256*196 = 50176
#define TILE 3125                 // 800000 / 256 exactly

typedef unsigned short ushort_t;

__device__ __forceinline__ ushort_t f32_to_bf16(float f) {
    unsigned u = __float_as_uint(f);
    u += 0x7fffu + ((u >> 16) & 1u);      // round-to-nearest-even
    return (ushort_t)(u >> 16);
}
// order-preserving float<->uint for atomicMax (finite floats; init 0 < any key)
__device__ __forceinline__ unsigned fkey(float f) {
    unsigned b = __float_as_uint(f);
    return (b & 0x80000000u) ? ~b : (b | 0x80000000u);
}
__device__ __forceinline__ float funkey(unsigned u) {
    unsigned b = (u & 0x80000000u) ? (u ^ 0x80000000u) : ~u;
    return __uint_as_float(b);
}

// ============================================================
// scan pass 1: per-1024-tile sums
// ============================================================
template<int N>
__global__ void scan_partial_g(const int* __restrict__ in, int* __restrict__ partials) {
    const int base = blockIdx.x * 1024 + threadIdx.x * 4;
    int4 c = make_int4(0, 0, 0, 0);
    if (base + 3 < N) c = *(const int4*)&in[base];
    else { int* cp = (int*)&c; for (int j = 0; j < 4; ++j) if (base + j < N) cp[j] = in[base + j]; }
    int s = c.x + c.y + c.z + c.w;
    #pragma unroll
    for (int off = 32; off >= 1; off >>= 1) s += __shfl_xor(s, off, 64);
    __shared__ int red[4];
    if ((threadIdx.x & 63) == 0) red[threadIdx.x >> 6] = s;
    __syncthreads();
    if (threadIdx.x == 0) partials[blockIdx.x] = red[0] + red[1] + red[2] + red[3];
}

// ============================================================
// scan pass 2 (fused): block re-scans <=64 raw partials in wave 0,
// then local scan + write.
// ============================================================
template<int N, int NT>
__global__ void scan_write_i(const int* __restrict__ in, const int* __restrict__ partials_raw,
                             int* __restrict__ out) {
    __shared__ int toff;
    __shared__ int sh[256];
    const int tid = threadIdx.x;
    if (tid < 64) {
        const int v = (tid < NT) ? partials_raw[tid] : 0;
        int inc = v;
        #pragma unroll
        for (int off = 1; off < 64; off <<= 1) {
            const int w = __shfl_up(inc, off, 64);
            if (tid >= off) inc += w;
        }
        if (tid == blockIdx.x) toff = inc - v;
    }
    const int base = blockIdx.x * 1024 + tid * 4;
    int4 c = make_int4(0, 0, 0, 0);
    if (base + 3 < N) c = *(const int4*)&in[base];
    else { int* cp = (int*)&c; for (int j = 0; j < 4; ++j) if (base + j < N) cp[j] = in[base + j]; }
    const int s = c.x + c.y + c.z + c.w;
    sh[tid] = s;
    __syncthreads();
    for (int off = 1; off < 256; off <<= 1) {
        const int w = (tid >= off) ? sh[tid - off] : 0;
        __syncthreads();
        sh[tid] += w;
        __syncthreads();
    }
    int run = toff + sh[tid] - s;
    const int* cp = (const int*)&c;
    int rp[4];
    #pragma unroll
    for (int j = 0; j < 4; ++j) { rp[j] = run; run += cp[j]; }
    if (base + 3 < N) *(int4*)&out[base] = make_int4(rp[0], rp[1], rp[2], rp[3]);
    else for (int j = 0; j < 4; ++j) if (base + j < N) out[base + j] = rp[j];
}

// ============================================================
// Bucketed edge partition (by dst bucket) — no global atomics
// ============================================================
__global__ __launch_bounds__(256) void bucket_hist(const int* __restrict__ dst,
                                                   int* __restrict__ Acnt) {
    __shared__ int hist[NB];
    for (int i = threadIdx.x; i < NB; i += 256) hist[i] = 0;
    __syncthreads();
    const int base = blockIdx.x * TILE;
    for (int i = threadIdx.x; i < TILE; i += 256)
        atomicAdd(&hist[dst[base + i] / BUCKET_NODES], 1);
    __syncthreads();
    for (int bk = threadIdx.x; bk < NB; bk += 256)
        Acnt[bk * NBLK + blockIdx.x] = hist[bk];
}

__global__ __launch_bounds__(256) void bucket_scatter(const int* __restrict__ src,
                                                      const int* __restrict__ dst,
                                                      const int* __restrict__ offs,
                                                      int2* __restrict__ staging) {
    __shared__ int cur[NB];
    for (int i = threadIdx.x; i < NB; i += 256) cur[i] = offs[i * NBLK + blockIdx.x];
    __syncthreads();
    const int base = blockIdx.x * TILE;
    for (int i = threadIdx.x; i < TILE; i += 256) {
        const int s = src[base + i], d = dst[base + i];
        const int pos = atomicAdd(&cur[d / BUCKET_NODES], 1);
        staging[pos] = make_int2(s, d);
    }
}

// ============================================================
// Per-bucket counting sort by src>>8 (ascending 32KB src windows
// for HBM row locality). Output packed: (src<<8) | dst_slot.
// ============================================================
__global__ __launch_bounds__(256) void sort_bucket(const int2* __restrict__ staging,
                                                   const int* __restrict__ offs,
                                                   unsigned* __restrict__ sorted_e) {
    __shared__ int bins[256];
    __shared__ int cur[256];
    const int b = blockIdx.x, tid = threadIdx.x;
    const int s0 = offs[b * NBLK];
    const int s1 = (b == NB - 1) ? N_EDGES : offs[(b + 1) * NBLK];
    bins[tid] = 0;
    __syncthreads();
    for (int i = s0 + tid; i < s1; i += 256)
        atomicAdd(&bins[staging[i].x >> 8], 1);          // src>>8 < 196
    __syncthreads();
    const int v = bins[tid];
    __shared__ int sc[256];
    sc[tid] = v;
    __syncthreads();
    for (int off = 1; off < 256; off <<= 1) {
        const int w = (tid >= off) ? sc[tid - off] : 0;
        __syncthreads();
        sc[tid] += w;
        __syncthreads();
    }
    cur[tid] = s0 + sc[tid] - v;                          // exclusive
    __syncthreads();
    for (int i = s0 + tid; i < s1; i += 256) {
        const int2 e = staging[i];
        const int pos = atomicAdd(&cur[e.x >> 8], 1);
        sorted_e[pos] = ((unsigned)e.x << 8) | (unsigned)(e.y - b * BUCKET_NODES);
    }
}

// ============================================================
// K1: z = h @ W.T + b — wave owns 8 rows, lane = output column.
//     z stored as bf16.
// ============================================================
#define NL_ROWS 8
__global__ __launch_bounds__(256) void node_linear_gemm(
    const float* __restrict__ h, ushort_t* __restrict__ zb,
    const float* __restrict__ W, const float* __restrict__ b,
    const float* __restrict__ a, const float* __restrict__ ab,
    float* __restrict__ s_src, float* __restrict__ s_dst)
{
    __shared__ float Wt[64 * 65];           // Wt[k*65 + j] = W[j*64 + k]
    for (int idx = threadIdx.x; idx < D * D; idx += 256) {
        const int j = idx >> 6, k = idx & 63;
        Wt[k * 65 + j] = W[idx];
    }
    __syncthreads();

    const int lane = threadIdx.x & 63;
    const int wv   = __builtin_amdgcn_readfirstlane(threadIdx.x >> 6);
    const int row0 = (blockIdx.x * 4 + wv) * NL_ROWS;
    if (row0 >= N_NODES) return;

    const float bj  = b[lane];
    const float alo = a[lane];
    const float ahi = a[64 + lane];

    const float* hr[NL_ROWS];
    #pragma unroll
    for (int r = 0; r < NL_ROWS; ++r) hr[r] = h + (size_t)(row0 + r) * D;

    float acc[NL_ROWS];
    #pragma unroll
    for (int r = 0; r < NL_ROWS; ++r) acc[r] = bj;

    #pragma unroll 4
    for (int k = 0; k < D; ++k) {
        const float wkj = Wt[k * 65 + lane];
        #pragma unroll
        for (int r = 0; r < NL_ROWS; ++r)
            acc[r] = fmaf(hr[r][k], wkj, acc[r]);
    }

    #pragma unroll
    for (int r = 0; r < NL_ROWS; ++r) {
        zb[(size_t)(row0 + r) * D + lane] = f32_to_bf16(acc[r]);
        float u = acc[r] * alo;
        float v = acc[r] * ahi;
        #pragma unroll
        for (int off = 32; off >= 1; off >>= 1) {
            u += __shfl_xor(u, off, 64);
            v += __shfl_xor(v, off, 64);
        }
        if (lane == 0) { s_src[row0 + r] = u; s_dst[row0 + r] = v + ab[0]; }
    }
}

// ============================================================
// K1b: gmax = max(s_src) — 64 blocks, one atomicMax per block.
// ============================================================
__global__ __launch_bounds__(256) void reduce_smax(const float* __restrict__ s_src,
                                                   unsigned* __restrict__ gmax_u) {
    __shared__ float red[4];
    const int tid = blockIdx.x * 256 + threadIdx.x;   // 64*256 = 16384 >= 12500
    float m = -INFINITY;
    if (tid * 4 + 3 < N_NODES) {
        const float4 v = *(const float4*)&s_src[tid * 4];
        m = fmaxf(fmaxf(v.x, v.y), fmaxf(v.z, v.w));
    } else {
        for (int j = tid * 4; j < min(tid * 4 + 4, N_NODES); ++j) m = fmaxf(m, s_src[j]);
    }
    #pragma unroll
    for (int off = 32; off >= 1; off >>= 1) m = fmaxf(m, __shfl_xor(m, off, 64));
    if ((threadIdx.x & 63) == 0) red[threadIdx.x >> 6] = m;
    __syncthreads();
    if (threadIdx.x == 0) {
        m = fmaxf(fmaxf(red[0], red[1]), fmaxf(red[2], red[3]));
        atomicMax(gmax_u, fkey(m));                   // 64 atomics total
    }
}

// ============================================================
// K2: bucket-resident aggregate. One block per dst-bucket:
//   acc[196][64] + den[196] live in LDS; edges streamed in
//   ASCENDING src order (sorted_e) -> zb reads are quasi-
//   sequential 128B rows (HBM row locality) instead of random.
//   UB-softmax: w = exp(e - leaky(gmax + s_dst)); divide at end.
// ============================================================
template<bool RELU>
__global__ __launch_bounds__(1024) void gat_bucket_agg(
    const unsigned* __restrict__ sorted_e, const int* __restrict__ offs,
    const float* __restrict__ s_src, const float* __restrict__ s_dst,
    const unsigned* __restrict__ gmax_u,
    const ushort_t* __restrict__ zb, float* __restrict__ out)
{
    __shared__ float accs[BUCKET_NODES][64];   // 50176 B
    __shared__ float dens[BUCKET_NODES];
    __shared__ float sdv[BUCKET_NODES];
    __shared__ float mub[BUCKET_NODES];
    __shared__ float wbuf[1024];
    __shared__ unsigned ebuf[1024];            // total ~60.7 KB

    const int b = blockIdx.x, tid = threadIdx.x;
    const float gmax = funkey(*gmax_u);

    for (int idx = tid; idx < BUCKET_NODES * 64; idx += 1024)
        ((float*)accs)[idx] = 0.f;
    if (tid < BUCKET_NODES) {
        dens[tid] = 0.f;
        const int node = b * BUCKET_NODES + tid;
        const float sd = (node < N_NODES) ? s_dst[node] : 0.f;
        sdv[tid] = sd;
        const float mu = gmax + sd;
        mub[tid] = mu > 0.f ? mu : 0.01f * mu;   // leaky(upper bound) >= all e
    }
    __syncthreads();

    const int s0 = offs[b * NBLK];
    const int s1 = (b == NB - 1) ? N_EDGES : offs[(b + 1) * NBLK];
    const int lane = tid & 63;
    const int wv   = tid >> 6;                 // 16 waves

    for (int base = s0; base < s1; base += 1024) {
        const int nE = min(1024, s1 - base);
        if (tid < nE) {
            const unsigned u = sorted_e[base + tid];
            const int src = u >> 8, slot = u & 255;
            float e = s_src[src] + sdv[slot];
            e = e > 0.f ? e : 0.01f * e;       // leaky_relu
            const float w = __expf(e - mub[slot]);
            wbuf[tid] = w;
            ebuf[tid] = u;
            atomicAdd(&dens[slot], w);         // LDS float atomic
        }
        __syncthreads();
        // feature phase: 16 waves interleave consecutive (ascending-src) edges
        #pragma unroll 4
        for (int j = wv; j < nE; j += 16) {
            const unsigned u = ebuf[j];
            const float w = wbuf[j];
            const int src = u >> 8, slot = u & 255;
            const float zf = __uint_as_float(((unsigned)zb[(size_t)src * D + lane]) << 16);
            atomicAdd(&accs[slot][lane], w * zf);   // consecutive addrs: conflict-free
        }
        __syncthreads();
    }

    // epilogue: divide + relu, fully coalesced writes (covers isolated nodes)
    for (int idx = tid; idx < BUCKET_NODES * 64; idx += 1024) {
        const int slot = idx >> 6, f = idx & 63;
        const int node = b * BUCKET_NODES + slot;
        if (node < N_NODES) {
            const float den = dens[slot];
            float v = (den > 0.f) ? accs[slot][f] / den : 0.f;
            if (RELU) v = fmaxf(v, 0.f);
            out[(size_t)node * D + f] = v;
        }
    }
}

// ============================================================
extern "C" void kernel_launch(void* const* d_in, const int* in_sizes, int n_in,
                              void* d_out, int out_size, void* d_ws, size_t ws_size,
                              hipStream_t stream) {
    const float* x   = (const float*)d_in[0];
    const int*   src = (const int*)d_in[1];
    const int*   dst = (const int*)d_in[2];
    float* out = (float*)d_out;

    // ---- workspace carve-out (256B-aligned slots) ----
    char* wp = (char*)d_ws;
    auto alloc = [&](size_t bytes) -> void* {
        void* p = (void*)wp;
        wp += (bytes + 255) & ~(size_t)255;
        return p;
    };
    ushort_t* zb      = (ushort_t*)alloc((size_t)N_NODES * D * sizeof(ushort_t));
    float* s_src      = (float*)alloc((size_t)N_NODES * sizeof(float));
    float* s_dst      = (float*)alloc((size_t)N_NODES * sizeof(float));
    int*   partB      = (int*)alloc(64 * sizeof(int));
    unsigned* gmax_u  = (unsigned*)alloc(4 * sizeof(unsigned));   // per-layer slots
    int*   Acnt       = (int*)alloc((size_t)NB * NBLK * sizeof(int));
    int*   offs       = (int*)alloc((size_t)NB * NBLK * sizeof(int));
    int2*  staging    = (int2*)alloc((size_t)N_EDGES * sizeof(int2));
    unsigned* sorted_e = (unsigned*)alloc((size_t)N_EDGES * sizeof(unsigned));
    (void)ws_size;

    hipMemsetAsync(gmax_u, 0, 4 * sizeof(unsigned), stream);   // 0 < fkey(any finite)

    // ---- edge partition + per-bucket src-sort: 5 dispatches ----
    bucket_hist<<<NBLK, 256, 0, stream>>>(dst, Acnt);
    scan_partial_g<NB * NBLK><<<64, 256, 0, stream>>>(Acnt, partB);
    scan_write_i<NB * NBLK, 64><<<64, 256, 0, stream>>>(Acnt, partB, offs);
    bucket_scatter<<<NBLK, 256, 0, stream>>>(src, dst, offs, staging);
    sort_bucket<<<NB, 256, 0, stream>>>(staging, offs, sorted_e);

    const int grid_k1 = (N_NODES + 4 * NL_ROWS - 1) / (4 * NL_ROWS);  // 1563

    for (int layer = 0; layer < 3; ++layer) {
        const float* W  = (const float*)d_in[3 + 4 * layer];
        const float* b  = (const float*)d_in[4 + 4 * layer];
        const float* a  = (const float*)d_in[5 + 4 * layer];
        const float* ab = (const float*)d_in[6 + 4 * layer];
        const float* hin = (layer == 0) ? x : out;   // d_out doubles as h buffer

        node_linear_gemm<<<grid_k1, 256, 0, stream>>>(hin, zb, W, b, a, ab, s_src, s_dst);
        reduce_smax<<<64, 256, 0, stream>>>(s_src, &gmax_u[layer]);
        if (layer < 2) {
            gat_bucket_agg<true ><<<NB, 1024, 0, stream>>>(sorted_e, offs, s_src, s_dst,
                                                           &gmax_u[layer], zb, out);
        } else {
            gat_bucket_agg<false><<<NB, 1024, 0, stream>>>(sorted_e, offs, s_src, s_dst,
                                                           &gmax_u[layer], zb, out);
        }
    }
}

// Round 19
// 197.408 us; speedup vs baseline: 4.9730x; 4.9730x over previous
//
#include <hip/hip_runtime.h>
#include <math.h>

#define N_NODES 50000
#define N_EDGES 800000
#define D 64

#define NB 256                    // dst buckets
#define NBLK 256                  // blocks in bucket hist/scatter
#define BUCKET_NODES 196          // ceil(50000/256); 256*196 = 50176
#define TILE 3125                 // 800000 / 256 exactly

typedef unsigned short ushort_t;

__device__ __forceinline__ ushort_t f32_to_bf16(float f) {
    unsigned u = __float_as_uint(f);
    u += 0x7fffu + ((u >> 16) & 1u);      // round-to-nearest-even
    return (ushort_t)(u >> 16);
}

// ============================================================
// scan pass 1: per-1024-tile sums
// ============================================================
template<int N>
__global__ void scan_partial_g(const int* __restrict__ in, int* __restrict__ partials) {
    const int base = blockIdx.x * 1024 + threadIdx.x * 4;
    int4 c = make_int4(0, 0, 0, 0);
    if (base + 3 < N) c = *(const int4*)&in[base];
    else { int* cp = (int*)&c; for (int j = 0; j < 4; ++j) if (base + j < N) cp[j] = in[base + j]; }
    int s = c.x + c.y + c.z + c.w;
    #pragma unroll
    for (int off = 32; off >= 1; off >>= 1) s += __shfl_xor(s, off, 64);
    __shared__ int red[4];
    if ((threadIdx.x & 63) == 0) red[threadIdx.x >> 6] = s;
    __syncthreads();
    if (threadIdx.x == 0) partials[blockIdx.x] = red[0] + red[1] + red[2] + red[3];
}

// ============================================================
// scan pass 2 (fused): each block re-scans the <=64 raw partials
// in wave 0, then does its local scan + write.
// ============================================================
template<int N, int NT>
__global__ void scan_write_i(const int* __restrict__ in, const int* __restrict__ partials_raw,
                             int* __restrict__ out) {
    __shared__ int toff;
    __shared__ int sh[256];
    const int tid = threadIdx.x;
    if (tid < 64) {
        const int v = (tid < NT) ? partials_raw[tid] : 0;
        int inc = v;
        #pragma unroll
        for (int off = 1; off < 64; off <<= 1) {
            const int w = __shfl_up(inc, off, 64);
            if (tid >= off) inc += w;
        }
        if (tid == blockIdx.x) toff = inc - v;   // exclusive tile offset (blockIdx < 64)
    }
    const int base = blockIdx.x * 1024 + tid * 4;
    int4 c = make_int4(0, 0, 0, 0);
    if (base + 3 < N) c = *(const int4*)&in[base];
    else { int* cp = (int*)&c; for (int j = 0; j < 4; ++j) if (base + j < N) cp[j] = in[base + j]; }
    const int s = c.x + c.y + c.z + c.w;
    sh[tid] = s;
    __syncthreads();
    for (int off = 1; off < 256; off <<= 1) {
        const int w = (tid >= off) ? sh[tid - off] : 0;
        __syncthreads();
        sh[tid] += w;
        __syncthreads();
    }
    int run = toff + sh[tid] - s;
    const int* cp = (const int*)&c;
    int rp[4];
    #pragma unroll
    for (int j = 0; j < 4; ++j) { rp[j] = run; run += cp[j]; }
    if (base + 3 < N) *(int4*)&out[base] = make_int4(rp[0], rp[1], rp[2], rp[3]);
    else for (int j = 0; j < 4; ++j) if (base + j < N) out[base + j] = rp[j];
}

// ============================================================
// Bucketed CSR build — no global atomics, XCD-local final writes
// ============================================================
__global__ __launch_bounds__(256) void bucket_hist(const int* __restrict__ dst,
                                                   int* __restrict__ Acnt) {
    __shared__ int hist[NB];
    for (int i = threadIdx.x; i < NB; i += 256) hist[i] = 0;
    __syncthreads();
    const int base = blockIdx.x * TILE;
    for (int i = threadIdx.x; i < TILE; i += 256)
        atomicAdd(&hist[dst[base + i] / BUCKET_NODES], 1);
    __syncthreads();
    for (int bk = threadIdx.x; bk < NB; bk += 256)
        Acnt[bk * NBLK + blockIdx.x] = hist[bk];
}

__global__ __launch_bounds__(256) void bucket_scatter(const int* __restrict__ src,
                                                      const int* __restrict__ dst,
                                                      const int* __restrict__ offs,
                                                      int2* __restrict__ staging) {
    __shared__ int cur[NB];
    for (int i = threadIdx.x; i < NB; i += 256) cur[i] = offs[i * NBLK + blockIdx.x];
    __syncthreads();
    const int base = blockIdx.x * TILE;
    for (int i = threadIdx.x; i < TILE; i += 256) {
        const int s = src[base + i], d = dst[base + i];
        const int pos = atomicAdd(&cur[d / BUCKET_NODES], 1);
        staging[pos] = make_int2(s, d);
    }
}

// node histogram per bucket (LDS) + per-bucket total
__global__ __launch_bounds__(256) void node_counts(const int2* __restrict__ staging,
                                                   const int* __restrict__ offs,
                                                   int* __restrict__ counts,
                                                   int* __restrict__ bucket_sum) {
    __shared__ int cnt[BUCKET_NODES];
    __shared__ int red[4];
    const int b = blockIdx.x, tid = threadIdx.x;
    for (int i = tid; i < BUCKET_NODES; i += 256) cnt[i] = 0;
    __syncthreads();
    const int s0 = offs[b * NBLK];
    const int s1 = (b == NB - 1) ? N_EDGES : offs[(b + 1) * NBLK];
    for (int i = s0 + tid; i < s1; i += 256)
        atomicAdd(&cnt[staging[i].y - b * BUCKET_NODES], 1);
    __syncthreads();
    for (int i = tid; i < BUCKET_NODES; i += 256) {
        const int node = b * BUCKET_NODES + i;
        if (node < N_NODES) counts[node] = cnt[i];
    }
    int s = (tid < BUCKET_NODES) ? cnt[tid] : 0;
    #pragma unroll
    for (int off = 32; off >= 1; off >>= 1) s += __shfl_xor(s, off, 64);
    if ((tid & 63) == 0) red[tid >> 6] = s;
    __syncthreads();
    if (tid == 0) bucket_sum[b] = red[0] + red[1] + red[2] + red[3];
}

// row_ptr from (bucket_sum scan) + (local counts scan); one kernel
__global__ __launch_bounds__(256) void row_ptr_build(const int* __restrict__ counts,
                                                     const int* __restrict__ bucket_sum,
                                                     int* __restrict__ row_ptr) {
    __shared__ int bs[NB];
    __shared__ int loc[256];
    const int b = blockIdx.x, tid = threadIdx.x;
    bs[tid] = bucket_sum[tid];                    // NB == 256 == blockDim
    __syncthreads();
    for (int off = 1; off < 256; off <<= 1) {     // inclusive scan of bucket sums
        const int w = (tid >= off) ? bs[tid - off] : 0;
        __syncthreads();
        bs[tid] += w;
        __syncthreads();
    }
    const int bucket_off = bs[b] - bucket_sum[b]; // exclusive offset of this bucket
    const int node = b * BUCKET_NODES + tid;
    const int c = (tid < BUCKET_NODES && node < N_NODES) ? counts[node] : 0;
    loc[tid] = c;
    __syncthreads();
    for (int off = 1; off < 256; off <<= 1) {     // inclusive scan of local counts
        const int w = (tid >= off) ? loc[tid - off] : 0;
        __syncthreads();
        loc[tid] += w;
        __syncthreads();
    }
    if (tid < BUCKET_NODES && node < N_NODES) row_ptr[node] = bucket_off + loc[tid] - c;
    if (b == 0 && tid == 0) row_ptr[N_NODES] = N_EDGES;
}

__global__ __launch_bounds__(256) void bucket_to_csr(const int2* __restrict__ staging,
                                                     const int* __restrict__ offs,
                                                     const int* __restrict__ row_ptr,
                                                     int* __restrict__ csr_src) {
    __shared__ int cur[BUCKET_NODES];
    const int b = blockIdx.x;
    for (int i = threadIdx.x; i < BUCKET_NODES; i += 256) {
        const int node = b * BUCKET_NODES + i;
        cur[i] = (node < N_NODES) ? row_ptr[node] : 0;
    }
    __syncthreads();
    const int s0 = offs[b * NBLK];
    const int s1 = (b == NB - 1) ? N_EDGES : offs[(b + 1) * NBLK];
    for (int i = s0 + threadIdx.x; i < s1; i += 256) {
        const int2 e = staging[i];
        const int pos = atomicAdd(&cur[e.y - b * BUCKET_NODES], 1);
        csr_src[pos] = e.x;
    }
}

// ============================================================
// K1: z = h @ W.T + b — wave owns 8 rows, lane = output column.
//     z stored as bf16.
// ============================================================
#define NL_ROWS 8
__global__ __launch_bounds__(256) void node_linear_gemm(
    const float* __restrict__ h, ushort_t* __restrict__ zb,
    const float* __restrict__ W, const float* __restrict__ b,
    const float* __restrict__ a, const float* __restrict__ ab,
    float* __restrict__ s_src, float* __restrict__ s_dst)
{
    __shared__ float Wt[64 * 65];           // Wt[k*65 + j] = W[j*64 + k]
    for (int idx = threadIdx.x; idx < D * D; idx += 256) {
        const int j = idx >> 6, k = idx & 63;
        Wt[k * 65 + j] = W[idx];
    }
    __syncthreads();

    const int lane = threadIdx.x & 63;
    const int wv   = __builtin_amdgcn_readfirstlane(threadIdx.x >> 6);
    const int row0 = (blockIdx.x * 4 + wv) * NL_ROWS;
    if (row0 >= N_NODES) return;

    const float bj  = b[lane];
    const float alo = a[lane];
    const float ahi = a[64 + lane];

    const float* hr[NL_ROWS];
    #pragma unroll
    for (int r = 0; r < NL_ROWS; ++r) hr[r] = h + (size_t)(row0 + r) * D;

    float acc[NL_ROWS];
    #pragma unroll
    for (int r = 0; r < NL_ROWS; ++r) acc[r] = bj;

    #pragma unroll 4
    for (int k = 0; k < D; ++k) {
        const float wkj = Wt[k * 65 + lane];
        #pragma unroll
        for (int r = 0; r < NL_ROWS; ++r)
            acc[r] = fmaf(hr[r][k], wkj, acc[r]);
    }

    #pragma unroll
    for (int r = 0; r < NL_ROWS; ++r) {
        zb[(size_t)(row0 + r) * D + lane] = f32_to_bf16(acc[r]);
        float u = acc[r] * alo;
        float v = acc[r] * ahi;
        #pragma unroll
        for (int off = 32; off >= 1; off >>= 1) {
            u += __shfl_xor(u, off, 64);
            v += __shfl_xor(v, off, 64);
        }
        if (lane == 0) { s_src[row0 + r] = u; s_dst[row0 + r] = v + ab[0]; }
    }
}

// ============================================================
// K2: FUSED softmax + weighted gather (+ReLU).
//   phase A: 4 nodes/wave, 16 lanes/node — online (m, den) only.
//   phase B: all 4 nodes' weight tables staged in DISJOINT LDS
//            regions, then ONE interleaved gather loop issuing
//            8 independent paired loads (2 edges × 4 nodes) per
//            step — ~4x memory-level parallelism vs sequential q.
// ============================================================
template<bool RELU>
__global__ __launch_bounds__(256) void fused_softmax_gather(
    const int* __restrict__ row_ptr, const int* __restrict__ csr_src,
    const float* __restrict__ s_src, const float* __restrict__ s_dst,
    const ushort_t* __restrict__ zb, float* __restrict__ out)
{
    __shared__ int2 sh[4][4][64];                  // [wave][node q][slot] = 8 KB
    const int lane = threadIdx.x & 63;
    const int wv   = threadIdx.x >> 6;
    const int g    = lane >> 4;                    // node group 0..3
    const int sl   = lane & 15;
    const int node0 = (blockIdx.x * 4 + wv) * 4;   // 50000 % 16 == 0, grid exact
    if (node0 >= N_NODES) return;
    const int mynode = node0 + g;

    // ---- phase A: online (m, den) for mynode (16 lanes each) ----
    const int beg = row_ptr[mynode];
    const int end = row_ptr[mynode + 1];
    const float sd = s_dst[mynode];
    float m = -INFINITY, den = 0.f;
    for (int base = beg; base < end; base += 16) {
        const int n = min(16, end - base);
        float e = -INFINITY;
        if (sl < n) {
            const int s = csr_src[base + sl];
            e = s_src[s] + sd;
            e = e > 0.f ? e : 0.01f * e;           // leaky_relu
        }
        float mc = e;
        #pragma unroll
        for (int off = 8; off >= 1; off >>= 1) mc = fmaxf(mc, __shfl_xor(mc, off, 64));
        if (mc > m) { den *= __expf(m - mc); m = mc; }
        float ex = (sl < n) ? __expf(e - m) : 0.f;
        #pragma unroll
        for (int off = 8; off >= 1; off >>= 1) ex += __shfl_xor(ex, off, 64);
        den += ex;
    }
    const float invden = (den > 0.f) ? 1.f / den : 0.f;

    // ---- broadcast per-node params to the whole wave ----
    int begq[4], endq[4];
    float mq[4], ivq[4], sdq[4];
    #pragma unroll
    for (int q = 0; q < 4; ++q) {
        begq[q] = __shfl(beg, q * 16, 64);
        endq[q] = __shfl(end, q * 16, 64);
        mq[q]   = __shfl(m, q * 16, 64);
        ivq[q]  = __shfl(invden, q * 16, 64);
        sdq[q]  = __shfl(sd, q * 16, 64);
    }
    int maxdeg = 0;
    #pragma unroll
    for (int q = 0; q < 4; ++q) maxdeg = max(maxdeg, endq[q] - begq[q]);

    // ---- phase B: interleaved 4-node gather ----
    const int half = lane >> 5;          // 0: even edges, 1: odd edges
    const int fl   = lane & 31;          // feature pair (2fl, 2fl+1)
    float2 acc[4][2];
    #pragma unroll
    for (int q = 0; q < 4; ++q) {
        acc[q][0] = make_float2(0.f, 0.f);
        acc[q][1] = make_float2(0.f, 0.f);
    }

    for (int c = 0; c < maxdeg; c += 64) {
        // stage all 4 nodes' (w, src) into disjoint LDS slabs
        #pragma unroll
        for (int q = 0; q < 4; ++q) {
            int2 ws = make_int2(0, 0);             // pad: weight 0, src 0 (L1-hot row)
            const int i = begq[q] + c + lane;
            if (i < endq[q]) {
                const int s = csr_src[i];
                float e = s_src[s] + sdq[q];
                e = e > 0.f ? e : 0.01f * e;
                ws = make_int2(__float_as_int(__expf(e - mq[q]) * ivq[q]), s);
            }
            sh[wv][q][lane] = ws;                  // wave-synchronous
        }
        const int n = min(64, maxdeg - c);
        for (int t = 0; t < n; t += 4) {           // 4 edges/node/iter
            #pragma unroll
            for (int q = 0; q < 4; ++q) {
                const int2 wa = sh[wv][q][t + half];
                const int2 wb = sh[wv][q][t + 2 + half];
                const unsigned ua = *(const unsigned*)&zb[(size_t)wa.y * D + 2 * fl];
                const unsigned ub = *(const unsigned*)&zb[(size_t)wb.y * D + 2 * fl];
                const float fa = __int_as_float(wa.x);
                const float fb = __int_as_float(wb.x);
                acc[q][0].x = fmaf(fa, __uint_as_float(ua << 16), acc[q][0].x);
                acc[q][0].y = fmaf(fa, __uint_as_float(ua & 0xffff0000u), acc[q][0].y);
                acc[q][1].x = fmaf(fb, __uint_as_float(ub << 16), acc[q][1].x);
                acc[q][1].y = fmaf(fb, __uint_as_float(ub & 0xffff0000u), acc[q][1].y);
            }
        }
    }
    #pragma unroll
    for (int q = 0; q < 4; ++q) {
        float2 tot = make_float2(acc[q][0].x + acc[q][1].x,
                                 acc[q][0].y + acc[q][1].y);
        tot.x += __shfl_xor(tot.x, 32, 64);        // merge even/odd halves
        tot.y += __shfl_xor(tot.y, 32, 64);
        if (RELU) { tot.x = fmaxf(tot.x, 0.f); tot.y = fmaxf(tot.y, 0.f); }
        if (half == 0)
            *(float2*)&out[(size_t)(node0 + q) * D + 2 * fl] = tot;
    }
}

// ============================================================
extern "C" void kernel_launch(void* const* d_in, const int* in_sizes, int n_in,
                              void* d_out, int out_size, void* d_ws, size_t ws_size,
                              hipStream_t stream) {
    const float* x   = (const float*)d_in[0];
    const int*   src = (const int*)d_in[1];
    const int*   dst = (const int*)d_in[2];
    float* out = (float*)d_out;

    // ---- workspace carve-out (256B-aligned slots, ~17 MB) ----
    char* wp = (char*)d_ws;
    auto alloc = [&](size_t bytes) -> void* {
        void* p = (void*)wp;
        wp += (bytes + 255) & ~(size_t)255;
        return p;
    };
    ushort_t* zb      = (ushort_t*)alloc((size_t)N_NODES * D * sizeof(ushort_t));
    float* s_src      = (float*)alloc((size_t)N_NODES * sizeof(float));
    float* s_dst      = (float*)alloc((size_t)N_NODES * sizeof(float));
    int*   counts     = (int*)alloc((size_t)N_NODES * sizeof(int));
    int*   row_ptr    = (int*)alloc((size_t)(N_NODES + 1) * sizeof(int));
    int*   csr_src    = (int*)alloc((size_t)N_EDGES * sizeof(int));
    int*   partB      = (int*)alloc(64 * sizeof(int));
    int*   bucket_sum = (int*)alloc((size_t)NB * sizeof(int));
    int*   Acnt       = (int*)alloc((size_t)NB * NBLK * sizeof(int));
    int*   offs       = (int*)alloc((size_t)NB * NBLK * sizeof(int));
    int2*  staging    = (int2*)alloc((size_t)N_EDGES * sizeof(int2));
    (void)ws_size;

    // ---- bucketed CSR build: 7 dispatches, zero global atomics ----
    bucket_hist<<<NBLK, 256, 0, stream>>>(dst, Acnt);
    scan_partial_g<NB * NBLK><<<64, 256, 0, stream>>>(Acnt, partB);
    scan_write_i<NB * NBLK, 64><<<64, 256, 0, stream>>>(Acnt, partB, offs);
    bucket_scatter<<<NBLK, 256, 0, stream>>>(src, dst, offs, staging);
    node_counts<<<NB, 256, 0, stream>>>(staging, offs, counts, bucket_sum);
    row_ptr_build<<<NB, 256, 0, stream>>>(counts, bucket_sum, row_ptr);
    bucket_to_csr<<<NB, 256, 0, stream>>>(staging, offs, row_ptr, csr_src);

    const int grid_k1 = (N_NODES + 4 * NL_ROWS - 1) / (4 * NL_ROWS);  // 1563
    const int grid_fg = N_NODES / 16;                                  // 3125 exact

    for (int layer = 0; layer < 3; ++layer) {
        const float* W  = (const float*)d_in[3 + 4 * layer];
        const float* b  = (const float*)d_in[4 + 4 * layer];
        const float* a  = (const float*)d_in[5 + 4 * layer];
        const float* ab = (const float*)d_in[6 + 4 * layer];
        const float* hin = (layer == 0) ? x : out;   // d_out doubles as h buffer

        node_linear_gemm<<<grid_k1, 256, 0, stream>>>(hin, zb, W, b, a, ab, s_src, s_dst);
        if (layer < 2) {
            fused_softmax_gather<true ><<<grid_fg, 256, 0, stream>>>(row_ptr, csr_src, s_src, s_dst, zb, out);
        } else {
            fused_softmax_gather<false><<<grid_fg, 256, 0, stream>>>(row_ptr, csr_src, s_src, s_dst, zb, out);
        }
    }
}